// Round 13
// baseline (212.467 us; speedup 1.0000x reference)
//
#include <hip/hip_runtime.h>
#include <math.h>

#define Bq 4
#define Nn 384
#define NB 1536   // Bq*Nn
#define TT 4
#define RR 4
#define HH 8
#define DKk 16
#define APART 12288   // att_part stride per i-tile: 32 bh * 384 j

typedef __attribute__((ext_vector_type(8))) short short8;
typedef __attribute__((ext_vector_type(4))) float f32x4;

__device__ __forceinline__ unsigned short f2bf(float f) {
  unsigned u = __float_as_uint(f);
  u += 0x7FFFu + ((u >> 16) & 1u);
  return (unsigned short)(u >> 16);
}

__device__ __forceinline__ void ld16(const float* __restrict__ p, float* o) {
  const float4* p4 = reinterpret_cast<const float4*>(p);
  float4 a = p4[0], b = p4[1], c = p4[2], d = p4[3];
  o[0]=a.x; o[1]=a.y; o[2]=a.z; o[3]=a.w;
  o[4]=b.x; o[5]=b.y; o[6]=b.z; o[7]=b.w;
  o[8]=c.x; o[9]=c.y; o[10]=c.z; o[11]=c.w;
  o[12]=d.x; o[13]=d.y; o[14]=d.z; o[15]=d.w;
}

// barrier that waits only LDS ops (lgkmcnt) — leaves register-destined global
// loads (vmcnt) in flight across the barrier (prefetch survives).
__device__ __forceinline__ void bar_lds() {
  asm volatile("s_waitcnt lgkmcnt(0)" ::: "memory");
  __builtin_amdgcn_s_barrier();
}

// layouts:
//  q_ws : [h][node][t*16+d]          64 f per (h,node)
//  kr_ws/vr_ws: [h][node][r*64+s*16+d]   256 f per (h,node)
//  kv_k/kv_v (aliases res_att, dead until k2): [node][t*128+c]
//  res_att: [b][h][i][j];  att_part: [it 24][bh][j]
//  agg  : [node][h*16+d]   (zeroed by k1b);  out zeroed by k1b too

// ---- K1a: QKV projection GEMM. Grid (24 node-tiles, 4 t, 3 proj), 256 thr.
__global__ __launch_bounds__(256) void k1a_qkv(
    const float* __restrict__ nf,
    const float* __restrict__ qw, const float* __restrict__ qb,
    const float* __restrict__ kw, const float* __restrict__ kb,
    const float* __restrict__ vw, const float* __restrict__ vb,
    float* __restrict__ q_ws, float* __restrict__ kv_k, float* __restrict__ kv_v)
{
  __shared__ float A_s[32][72];    // [k][node]
  __shared__ float W_s[32][132];   // [k][col]
  int mt = blockIdx.x, t = blockIdx.y, z = blockIdx.z;
  const float* W    = (z == 0) ? qw : ((z == 1) ? kw : vw);
  const float* bias = (z == 0) ? qb : ((z == 1) ? kb : vb);
  int tid = threadIdx.x;
  int colq = (tid & 31)*4, n8 = (tid >> 5)*8;
  float acc[8][4];
#pragma unroll
  for (int u = 0; u < 8; ++u)
#pragma unroll
    for (int c = 0; c < 4; ++c) acc[u][c] = 0.f;

  for (int kc = 0; kc < 4; ++kc) {
    __syncthreads();
    {
      int kk = tid & 31, nb0 = tid >> 5;
#pragma unroll
      for (int u = 0; u < 8; ++u)
        A_s[kk][nb0 + u*8] = nf[(size_t)(mt*64 + nb0 + u*8)*128 + kc*32 + kk];
#pragma unroll
      for (int u = 0; u < 4; ++u) {
        int idx = u*256 + tid;
        int wk = idx >> 5, c4 = (idx & 31)*4;
        *(float4*)&W_s[wk][c4] = *(const float4*)&W[(size_t)(t*128 + kc*32 + wk)*128 + c4];
      }
    }
    __syncthreads();
#pragma unroll
    for (int k = 0; k < 32; ++k) {
      float4 w4 = *(float4*)&W_s[k][colq];
      float a0[8];
      *(float4*)&a0[0] = *(float4*)&A_s[k][n8];
      *(float4*)&a0[4] = *(float4*)&A_s[k][n8 + 4];
#pragma unroll
      for (int u = 0; u < 8; ++u) {
        acc[u][0] += a0[u]*w4.x; acc[u][1] += a0[u]*w4.y;
        acc[u][2] += a0[u]*w4.z; acc[u][3] += a0[u]*w4.w;
      }
    }
  }
  float4 bv = *(const float4*)&bias[t*128 + colq];
#pragma unroll
  for (int u = 0; u < 8; ++u) {
    int node = mt*64 + n8 + u;
    float4 o;
    o.x = acc[u][0] + bv.x; o.y = acc[u][1] + bv.y;
    o.z = acc[u][2] + bv.z; o.w = acc[u][3] + bv.w;
    if (z == 0) {
      int h = colq >> 4, d = colq & 15;
      *(float4*)&q_ws[((size_t)h*NB + node)*64 + t*16 + d] = o;
    } else {
      float* dst = (z == 1) ? kv_k : kv_v;
      *(float4*)&dst[(size_t)node*512 + t*128 + colq] = o;
    }
  }
}

// ---- K1b: kr/vr relation transform + zero agg & out slices. Grid (96, 8).
__global__ __launch_bounds__(256) void k1b_rel(
    const float* __restrict__ kv_k, const float* __restrict__ kv_v,
    const float* __restrict__ rel_att, const float* __restrict__ rel_msg,
    float* __restrict__ kr_ws, float* __restrict__ vr_ws,
    float* __restrict__ agg, float* __restrict__ out)
{
  __shared__ float ra_s[4][16][16];
  __shared__ float rm_s[4][16][16];
  __shared__ float k_s[16][4][17];
  __shared__ float v_s[16][4][17];
  int nb = blockIdx.x, h = blockIdx.y;
  int n0 = nb*16;
  int tid = threadIdx.x;
  // zero this block's agg + out slices (replaces memset; out needed for k5 atomics)
  agg[(size_t)(n0 + (tid >> 4))*128 + h*16 + (tid & 15)] = 0.f;
  out[(size_t)(n0 + (tid >> 4))*128 + h*16 + (tid & 15)] = 0.f;
#pragma unroll
  for (int u0 = 0; u0 < 4; ++u0) {
    int u = u0*256 + tid;
    int r = u >> 8, e = (u >> 4) & 15, d = u & 15;
    ra_s[r][e][d] = rel_att[((size_t)(r*8 + h)*16 + e)*16 + d];
    rm_s[r][e][d] = rel_msg[((size_t)(r*8 + h)*16 + e)*16 + d];
    int nl = u >> 6, s = (u >> 4) & 3, e2 = u & 15;
    k_s[nl][s][e2] = kv_k[(size_t)(n0 + nl)*512 + s*128 + h*16 + e2];
    v_s[nl][s][e2] = kv_v[(size_t)(n0 + nl)*512 + s*128 + h*16 + e2];
  }
  __syncthreads();
  int nl = tid >> 4, dq = tid & 15;
  size_t obase = ((size_t)h*NB + n0 + nl)*256;
#pragma unroll
  for (int r = 0; r < 4; ++r)
#pragma unroll
    for (int s = 0; s < 4; ++s) {
      float aK = 0.f, aV = 0.f;
#pragma unroll
      for (int e = 0; e < 16; ++e) {
        aK += k_s[nl][s][e] * ra_s[r][e][dq];
        aV += v_s[nl][s][e] * rm_s[r][e][dq];
      }
      kr_ws[obase + r*64 + s*16 + dq] = aK;
      vr_ws[obase + r*64 + s*16 + dq] = aV;
    }
}

// ---- K2: res_att[b,h,i,j] + per-tile column sums (fp32, precision-critical).
__global__ __launch_bounds__(256,2) void k2_att(
    const float* __restrict__ nt, const float* __restrict__ adj,
    const float* __restrict__ ets, const float* __restrict__ rel_pri,
    const float* __restrict__ q_ws, const float* __restrict__ kr_ws,
    float* __restrict__ res_att, float* __restrict__ att_part)
{
  __shared__ float q_s[16*68];
  __shared__ float kr_s[32*260];
  __shared__ float ntj_s[32*4];
  int bx = blockIdx.x, h = blockIdx.y, b = blockIdx.z;
  int it = bx >> 1, jh = bx & 1;
  int i0 = it*16;
  int tid = threadIdx.x;
  int j_l = tid>>3, ig = (tid>>1)&3, dh = tid&1;
  // stage q (identity copy, layout [i][t*16+d], row stride 68)
  {
    int i = tid>>4, f = (tid&15)*4;
    float4 qv = *(const float4*)&q_ws[((size_t)(h*NB) + b*Nn + i0 + i)*64 + f];
    *(float4*)&q_s[i*68 + f] = qv;
  }
  // nti in registers: ntiv[il][s]
  float ntiv[4][4];
#pragma unroll
  for (int il = 0; il < 4; ++il) {
    float4 v = *(const float4*)&nt[(size_t)(b*Nn + i0 + ig*4 + il)*TT];
    ntiv[il][0]=v.x; ntiv[il][1]=v.y; ntiv[il][2]=v.z; ntiv[il][3]=v.w;
  }
  float crr[4];
#pragma unroll
  for (int r = 0; r < 4; ++r) crr[r] = rel_pri[r*HH+h]*0.25f;

  for (int jc = jh*6; jc < jh*6 + 6; ++jc) {
    __syncthreads();
    {
      int js = tid>>3, gb = tid&7;
      const float* src = &kr_ws[((size_t)(h*NB) + b*Nn + jc*32 + js)*256];
      float* dst = &kr_s[js*260];
#pragma unroll
      for (int gl = 0; gl < 8; ++gl) {
        int g = gl*8 + gb;
        *(float4*)&dst[g*4] = *(const float4*)&src[g*4];
      }
      if (tid < 128) ntj_s[tid] = nt[(size_t)(b*Nn + jc*32 + (tid>>2))*TT + (tid&3)];
    }
    __syncthreads();
    int j = jc*32 + j_l;
    float nt0 = ntj_s[j_l*4+0], nt1 = ntj_s[j_l*4+1];
    float nt2 = ntj_s[j_l*4+2], nt3 = ntj_s[j_l*4+3];
    // qn fold: 8 x ds_read_b128 per il on [t*16 + dh*8] windows
    float qn[4][8];
#pragma unroll
    for (int il = 0; il < 4; ++il) {
      const float* qb2 = &q_s[(ig*4 + il)*68 + dh*8];
      float4 a0 = *(const float4*)&qb2[0],  a1 = *(const float4*)&qb2[4];
      float4 b0 = *(const float4*)&qb2[16], b1 = *(const float4*)&qb2[20];
      float4 c0 = *(const float4*)&qb2[32], c1 = *(const float4*)&qb2[36];
      float4 d0v = *(const float4*)&qb2[48], d1v = *(const float4*)&qb2[52];
      qn[il][0] = a0.x*nt0 + b0.x*nt1 + c0.x*nt2 + d0v.x*nt3;
      qn[il][1] = a0.y*nt0 + b0.y*nt1 + c0.y*nt2 + d0v.y*nt3;
      qn[il][2] = a0.z*nt0 + b0.z*nt1 + c0.z*nt2 + d0v.z*nt3;
      qn[il][3] = a0.w*nt0 + b0.w*nt1 + c0.w*nt2 + d0v.w*nt3;
      qn[il][4] = a1.x*nt0 + b1.x*nt1 + c1.x*nt2 + d1v.x*nt3;
      qn[il][5] = a1.y*nt0 + b1.y*nt1 + c1.y*nt2 + d1v.y*nt3;
      qn[il][6] = a1.z*nt0 + b1.z*nt1 + c1.z*nt2 + d1v.z*nt3;
      qn[il][7] = a1.w*nt0 + b1.w*nt1 + c1.w*nt2 + d1v.w*nt3;
    }
    float mar[4][4];
#pragma unroll
    for (int il = 0; il < 4; ++il) {
      int i = i0 + ig*4 + il;
      float a = adj[((size_t)b*Nn + i)*Nn + j];
      float4 e4 = *(const float4*)&ets[(((size_t)b*Nn + i)*Nn + j)*RR];
      mar[il][0]=e4.x*a; mar[il][1]=e4.y*a; mar[il][2]=e4.z*a; mar[il][3]=e4.w*a;
    }
    float acc[4] = {0.f,0.f,0.f,0.f};
    const float* kbp = &kr_s[j_l*260 + dh*8];
#pragma unroll
    for (int r = 0; r < 4; ++r) {
      float mr0 = mar[0][r]*crr[r], mr1 = mar[1][r]*crr[r];
      float mr2 = mar[2][r]*crr[r], mr3 = mar[3][r]*crr[r];
#pragma unroll
      for (int s = 0; s < 4; ++s) {
        float kk[8];
        *(float4*)&kk[0] = *(const float4*)&kbp[r*64 + s*16];
        *(float4*)&kk[4] = *(const float4*)&kbp[r*64 + s*16 + 4];
        float d0=0,d1=0,d2=0,d3=0;
#pragma unroll
        for (int dp = 0; dp < 8; ++dp) {
          d0 += qn[0][dp]*kk[dp]; d1 += qn[1][dp]*kk[dp];
          d2 += qn[2][dp]*kk[dp]; d3 += qn[3][dp]*kk[dp];
        }
        acc[0] += mr0*ntiv[0][s]*d0;
        acc[1] += mr1*ntiv[1][s]*d1;
        acc[2] += mr2*ntiv[2][s]*d2;
        acc[3] += mr3*ntiv[3][s]*d3;
      }
    }
    // combine dh halves (coefficients identical across the pair, sum distributes)
#pragma unroll
    for (int il = 0; il < 4; ++il)
      acc[il] += __shfl_xor(acc[il], 1);
    if (dh == 0) {
#pragma unroll
      for (int il = 0; il < 4; ++il)
        res_att[((size_t)(b*HH + h)*Nn + i0 + ig*4 + il)*Nn + j] = acc[il];
    }
    float v = acc[0] + acc[1] + acc[2] + acc[3];
    v += __shfl_xor(v, 2);
    v += __shfl_xor(v, 4);
    if ((tid & 7) == 0)
      att_part[(size_t)it*APART + (size_t)(b*HH + h)*Nn + j] = v;
  }
}

// ---- KC: MFMA message pass. Grid (it 3, jc 6, bh 32), 512 thr (8 waves).
// 8 waves cover 128 i-rows sharing ONE staged B/vr per r-phase. Staging split:
// threads 0-255 build B (kr*ntj*cr), threads 256-511 transpose vr.
__global__ __launch_bounds__(512, 4) void kc_agg(
    const float* __restrict__ nt, const float* __restrict__ adj,
    const float* __restrict__ ets, const float* __restrict__ rel_pri,
    const float* __restrict__ q_ws, const float* __restrict__ kr_ws,
    const float* __restrict__ vr_ws, const float* __restrict__ res_att,
    const float* __restrict__ att_part, float* __restrict__ agg)
{
  __shared__ __align__(16) unsigned short B_lds[4][64*72];
  __shared__ __align__(16) unsigned short vr_lds[64*72];
  __shared__ __align__(16) unsigned short Z_lds[8][16*72];
  __shared__ float inv_s[64];
  int it = blockIdx.x, jc = blockIdx.y, bh = blockIdx.z;
  int b = bh >> 3, h = bh & 7;
  int tid = threadIdx.x, w = tid >> 6, l = tid & 63;
  int j0 = jc*64;
  int ib = it*128 + w*16;
  int irow = ib + (l & 15);
  int iz = ib + ((l >> 4) << 2);
  int lq = (l >> 4) * 8;
  if (tid < 64) {
    float s = 0.f;
#pragma unroll
    for (int p = 0; p < 24; ++p)
      s += att_part[(size_t)p*APART + (size_t)bh*Nn + j0 + tid];
    inv_s[tid] = (s > 1e-6f) ? 1.f/s : 0.f;
  }
  // A fragments: af[s][kk] = bf16(q[irow, k] * nti[irow, s])
  short8 af[4][2];
  {
    float q0[8], q1[8];
    const float* qp = &q_ws[((size_t)h*NB + b*Nn + irow)*64];
    *(float4*)&q0[0] = *(const float4*)&qp[lq];
    *(float4*)&q0[4] = *(const float4*)&qp[lq + 4];
    *(float4*)&q1[0] = *(const float4*)&qp[32 + lq];
    *(float4*)&q1[4] = *(const float4*)&qp[32 + lq + 4];
    float4 ntiv = *(const float4*)&nt[(size_t)(b*Nn + irow)*4];
    float nta[4] = {ntiv.x, ntiv.y, ntiv.z, ntiv.w};
#pragma unroll
    for (int s = 0; s < 4; ++s)
#pragma unroll
      for (int e = 0; e < 8; ++e) {
        af[s][0][e] = (short)f2bf(q0[e]*nta[s]);
        af[s][1][e] = (short)f2bf(q1[e]*nta[s]);
      }
  }
  float crv[4];
#pragma unroll
  for (int r = 0; r < 4; ++r) crv[r] = rel_pri[r*HH + h]*0.25f;
  // pre-barrier: cw0 = res_att*adj (global only); ets offsets
  float cw[4][4];
  int eo[4][4];
  const float* ebase = ets + (size_t)b*Nn*Nn*4;
#pragma unroll
  for (int tj = 0; tj < 4; ++tj) {
    int j = j0 + tj*16 + (l & 15);
#pragma unroll
    for (int p = 0; p < 4; ++p) {
      int i = iz + p;
      cw[tj][p] = res_att[((size_t)bh*Nn + i)*Nn + j]
                * adj[((size_t)b*Nn + i)*Nn + j];
      eo[tj][p] = (i*Nn + j)*4;
    }
  }
  f32x4 agg_acc = {0.f,0.f,0.f,0.f};
  // staging: half the threads do B, half do vr. Identical LDS patterns to the
  // proven 256-thread version; each group stages 64 nodes x 4 chunks of 16 f.
  int sj = (tid & 255) >> 2, ss = tid & 3;
  bool doB = (tid < 256);
  const float* srcp = doB
      ? &kr_ws[((size_t)h*NB + b*Nn + j0 + sj)*256 + ss*16]
      : &vr_ws[((size_t)h*NB + b*Nn + j0 + sj)*256 + ss*16];
  float vA[16];
  ld16(srcp, vA);
  float4 ntjv = *(const float4*)&nt[(size_t)(b*Nn + j0 + sj)*4];
  bar_lds();   // inv_s visible
  // finish cw with inv
#pragma unroll
  for (int tj = 0; tj < 4; ++tj) {
    float inv = inv_s[tj*16 + (l & 15)];
#pragma unroll
    for (int p = 0; p < 4; ++p) cw[tj][p] *= inv;
  }

#pragma unroll
  for (int r = 0; r < 4; ++r) {
    if (r) bar_lds();   // previous compute's LDS reads done before overwrite
    // STAGE r
    if (doB) {
      float crr = crv[r];
      float nta[4] = {ntjv.x*crr, ntjv.y*crr, ntjv.z*crr, ntjv.w*crr};
#pragma unroll
      for (int t = 0; t < 4; ++t) {
#pragma unroll
        for (int dq = 0; dq < 2; ++dq) {
          short8 v;
#pragma unroll
          for (int e = 0; e < 8; ++e) v[e] = (short)f2bf(vA[dq*8 + e]*nta[t]);
          *(short8*)&B_lds[ss][sj*72 + t*16 + dq*8] = v;
        }
      }
    } else {
#pragma unroll
      for (int d = 0; d < 16; ++d)
        vr_lds[(ss*16 + d)*72 + sj] = f2bf(vA[d]);
    }
    // prefetch r+1 into registers (stays in flight across barrier)
    float vB[16];
    if (r < 3) ld16(srcp + (r+1)*64, vB);
    bar_lds();
    // COMPUTE r
    float coef[4][4];
#pragma unroll
    for (int tj = 0; tj < 4; ++tj)
#pragma unroll
      for (int p = 0; p < 4; ++p)
        coef[tj][p] = ebase[eo[tj][p] + r] * cw[tj][p];
#pragma unroll
    for (int s = 0; s < 4; ++s) {
      f32x4 wacc[4];
#pragma unroll
      for (int tj = 0; tj < 4; ++tj) wacc[tj] = (f32x4){0.f,0.f,0.f,0.f};
#pragma unroll
      for (int tj = 0; tj < 4; ++tj) {
        short8 b0 = *(const short8*)&B_lds[s][(tj*16 + (l & 15))*72 + lq];
        short8 b1 = *(const short8*)&B_lds[s][(tj*16 + (l & 15))*72 + 32 + lq];
        wacc[tj] = __builtin_amdgcn_mfma_f32_16x16x32_bf16(af[s][0], b0, wacc[tj], 0, 0, 0);
        wacc[tj] = __builtin_amdgcn_mfma_f32_16x16x32_bf16(af[s][1], b1, wacc[tj], 0, 0, 0);
      }
#pragma unroll
      for (int tj = 0; tj < 4; ++tj)
#pragma unroll
        for (int p = 0; p < 4; ++p)
          Z_lds[w][(((l >> 4)*4) + p)*72 + tj*16 + (l & 15)] = f2bf(wacc[tj][p]*coef[tj][p]);
#pragma unroll
      for (int kj = 0; kj < 2; ++kj) {
        short8 zf = *(const short8*)&Z_lds[w][(l & 15)*72 + kj*32 + lq];
        short8 vf = *(const short8*)&vr_lds[(s*16 + (l & 15))*72 + kj*32 + lq];
        agg_acc = __builtin_amdgcn_mfma_f32_16x16x32_bf16(zf, vf, agg_acc, 0, 0, 0);
      }
    }
    if (r < 3) {
#pragma unroll
      for (int e = 0; e < 16; ++e) vA[e] = vB[e];
    }
  }
#pragma unroll
  for (int p = 0; p < 4; ++p)
    atomicAdd(&agg[((size_t)b*Nn + iz + p)*128 + h*16 + (l & 15)], agg_acc[p]);
}

// K5: trans = agg.aw + ab, GELU, skip-gate, LayerNorm, type-mix.
// Grid (384 node-quads, 4 t), 128 thr = (group g 4 nodes, o-quad 32).
__global__ __launch_bounds__(128) void k5_out(
    const float* __restrict__ agg_ws, const float* __restrict__ nf,
    const float* __restrict__ nt, const float* __restrict__ aw,
    const float* __restrict__ ab, const float* __restrict__ norm_w,
    const float* __restrict__ norm_b, const float* __restrict__ skip,
    float* __restrict__ out)
{
  __shared__ float agg_s[4][128];
  int nq = blockIdx.x, t = blockIdx.y;
  int tid = threadIdx.x;
  int g = tid >> 5, o0 = (tid & 31)*4;
  {
    int nl = tid >> 5, c = (tid & 31)*4;
    *(float4*)&agg_s[nl][c] = *(const float4*)&agg_ws[(size_t)(nq*4 + nl)*128 + c];
  }
  __syncthreads();
  size_t node = (size_t)nq*4 + g;
  float alpha = 1.f/(1.f + expf(-skip[t]));
  float4 bv = *(const float4*)&ab[t*128 + o0];
  float a0 = bv.x, a1 = bv.y, a2 = bv.z, a3 = bv.w;
  const float* awt = aw + (size_t)t*128*128;
  for (int dd = 0; dd < 128; ++dd) {
    float av = agg_s[g][dd];
    float4 wv = *(const float4*)&awt[dd*128 + o0];
    a0 += av*wv.x; a1 += av*wv.y; a2 += av*wv.z; a3 += av*wv.w;
  }
  float4 nfv = *(const float4*)&nf[node*128 + o0];
  float av4[4] = {a0, a1, a2, a3};
  float nfa[4] = {nfv.x, nfv.y, nfv.z, nfv.w};
  float res[4];
#pragma unroll
  for (int c = 0; c < 4; ++c) {
    float gl = 0.5f*av4[c]*(1.f + erff(av4[c]*0.70710678118654752f));
    res[c] = gl*alpha + nfa[c]*(1.f - alpha);
  }
  float s1 = res[0]+res[1]+res[2]+res[3];
  float s2 = res[0]*res[0]+res[1]*res[1]+res[2]*res[2]+res[3]*res[3];
#pragma unroll
  for (int m = 16; m >= 1; m >>= 1) { s1 += __shfl_xor(s1, m); s2 += __shfl_xor(s2, m); }
  float mean = s1*(1.f/128.f);
  float var  = s2*(1.f/128.f) - mean*mean;
  float rstd = rsqrtf(var + 1e-5f);
  float ntv = nt[node*TT + t];
  float4 nwv = *(const float4*)&norm_w[t*128 + o0];
  float4 nbv = *(const float4*)&norm_b[t*128 + o0];
  float nww[4] = {nwv.x, nwv.y, nwv.z, nwv.w};
  float nbb[4] = {nbv.x, nbv.y, nbv.z, nbv.w};
#pragma unroll
  for (int c = 0; c < 4; ++c) {
    float nrm = (res[c] - mean)*rstd*nww[c] + nbb[c];
    atomicAdd(&out[node*128 + o0 + c], nrm*ntv);
  }
}

extern "C" void kernel_launch(void* const* d_in, const int* in_sizes, int n_in,
                              void* d_out, int out_size, void* d_ws, size_t ws_size,
                              hipStream_t stream) {
  const float* nf      = (const float*)d_in[0];
  const float* nts     = (const float*)d_in[1];
  const float* adj     = (const float*)d_in[2];
  const float* ets     = (const float*)d_in[3];
  const float* kw      = (const float*)d_in[4];
  const float* kb      = (const float*)d_in[5];
  const float* qw      = (const float*)d_in[6];
  const float* qb      = (const float*)d_in[7];
  const float* vw      = (const float*)d_in[8];
  const float* vb      = (const float*)d_in[9];
  const float* aw      = (const float*)d_in[10];
  const float* ab      = (const float*)d_in[11];
  const float* normw   = (const float*)d_in[12];
  const float* normb   = (const float*)d_in[13];
  const float* rel_pri = (const float*)d_in[14];
  const float* rel_att = (const float*)d_in[15];
  const float* rel_msg = (const float*)d_in[16];
  const float* skip    = (const float*)d_in[17];
  (void)in_sizes; (void)n_in; (void)out_size; (void)ws_size;

  float* ws = (float*)d_ws;
  float* q_ws    = ws;                        // 786432
  float* kr_ws   = q_ws + 786432;             // 3145728
  float* vr_ws   = kr_ws + 3145728;           // 3145728
  float* res_att = vr_ws + 3145728;           // 4718592
  float* att_part= res_att + 4718592;         // 294912 (24 x 12288)
  float* agg_ws  = att_part + 294912 + 12288; // 196608
  // kv scratch aliases res_att (dead until k2 writes it)
  float* kv_k = res_att;                      // 786432
  float* kv_v = res_att + 786432;             // 786432

  hipLaunchKernelGGL(k1a_qkv, dim3(24, 4, 3), dim3(256), 0, stream,
                     nf, qw, qb, kw, kb, vw, vb, q_ws, kv_k, kv_v);
  hipLaunchKernelGGL(k1b_rel, dim3(96, 8), dim3(256), 0, stream,
                     kv_k, kv_v, rel_att, rel_msg, kr_ws, vr_ws, agg_ws, (float*)d_out);
  hipLaunchKernelGGL(k2_att, dim3(48, 8, 4), dim3(256), 0, stream,
                     nts, adj, ets, rel_pri, q_ws, kr_ws, res_att, att_part);
  hipLaunchKernelGGL(kc_agg, dim3(3, 6, 32), dim3(512), 0, stream,
                     nts, adj, ets, rel_pri, q_ws, kr_ws, vr_ws, res_att, att_part, agg_ws);
  hipLaunchKernelGGL(k5_out, dim3(384, 4), dim3(128), 0, stream,
                     agg_ws, nf, nts, aw, ab, normw, normb, skip, (float*)d_out);
}

// Round 14
// 197.359 us; speedup vs baseline: 1.0766x; 1.0766x over previous
//
#include <hip/hip_runtime.h>
#include <math.h>

#define Bq 4
#define Nn 384
#define NB 1536   // Bq*Nn
#define TT 4
#define RR 4
#define HH 8
#define DKk 16
#define APART 12288   // att_part stride per i-tile: 32 bh * 384 j

typedef __attribute__((ext_vector_type(8))) short short8;
typedef __attribute__((ext_vector_type(4))) float f32x4;

__device__ __forceinline__ unsigned short f2bf(float f) {
  unsigned u = __float_as_uint(f);
  u += 0x7FFFu + ((u >> 16) & 1u);
  return (unsigned short)(u >> 16);
}

__device__ __forceinline__ void ld16(const float* __restrict__ p, float* o) {
  const float4* p4 = reinterpret_cast<const float4*>(p);
  float4 a = p4[0], b = p4[1], c = p4[2], d = p4[3];
  o[0]=a.x; o[1]=a.y; o[2]=a.z; o[3]=a.w;
  o[4]=b.x; o[5]=b.y; o[6]=b.z; o[7]=b.w;
  o[8]=c.x; o[9]=c.y; o[10]=c.z; o[11]=c.w;
  o[12]=d.x; o[13]=d.y; o[14]=d.z; o[15]=d.w;
}

// barrier that waits only LDS ops (lgkmcnt) — leaves register-destined global
// loads (vmcnt) in flight across the barrier (prefetch survives).
__device__ __forceinline__ void bar_lds() {
  asm volatile("s_waitcnt lgkmcnt(0)" ::: "memory");
  __builtin_amdgcn_s_barrier();
}

// layouts:
//  q_ws : [h][node][t*16+d]          64 f per (h,node)
//  kr_ws/vr_ws: [h][node][r*64+s*16+d]   256 f per (h,node)
//  kv_k/kv_v (aliases res_att, dead until k2): [node][t*128+c]
//  res_att: [b][h][i][j];  att_part: [it 24][bh][j]
//  agg  : [node][h*16+d]   (zeroed by k1b);  out zeroed by k1b too

// ---- K1a: QKV projection GEMM. Grid (24 node-tiles, 4 t, 3 proj), 256 thr.
__global__ __launch_bounds__(256) void k1a_qkv(
    const float* __restrict__ nf,
    const float* __restrict__ qw, const float* __restrict__ qb,
    const float* __restrict__ kw, const float* __restrict__ kb,
    const float* __restrict__ vw, const float* __restrict__ vb,
    float* __restrict__ q_ws, float* __restrict__ kv_k, float* __restrict__ kv_v)
{
  __shared__ float A_s[32][72];    // [k][node]
  __shared__ float W_s[32][132];   // [k][col]
  int mt = blockIdx.x, t = blockIdx.y, z = blockIdx.z;
  const float* W    = (z == 0) ? qw : ((z == 1) ? kw : vw);
  const float* bias = (z == 0) ? qb : ((z == 1) ? kb : vb);
  int tid = threadIdx.x;
  int colq = (tid & 31)*4, n8 = (tid >> 5)*8;
  float acc[8][4];
#pragma unroll
  for (int u = 0; u < 8; ++u)
#pragma unroll
    for (int c = 0; c < 4; ++c) acc[u][c] = 0.f;

  for (int kc = 0; kc < 4; ++kc) {
    __syncthreads();
    {
      int kk = tid & 31, nb0 = tid >> 5;
#pragma unroll
      for (int u = 0; u < 8; ++u)
        A_s[kk][nb0 + u*8] = nf[(size_t)(mt*64 + nb0 + u*8)*128 + kc*32 + kk];
#pragma unroll
      for (int u = 0; u < 4; ++u) {
        int idx = u*256 + tid;
        int wk = idx >> 5, c4 = (idx & 31)*4;
        *(float4*)&W_s[wk][c4] = *(const float4*)&W[(size_t)(t*128 + kc*32 + wk)*128 + c4];
      }
    }
    __syncthreads();
#pragma unroll
    for (int k = 0; k < 32; ++k) {
      float4 w4 = *(float4*)&W_s[k][colq];
      float a0[8];
      *(float4*)&a0[0] = *(float4*)&A_s[k][n8];
      *(float4*)&a0[4] = *(float4*)&A_s[k][n8 + 4];
#pragma unroll
      for (int u = 0; u < 8; ++u) {
        acc[u][0] += a0[u]*w4.x; acc[u][1] += a0[u]*w4.y;
        acc[u][2] += a0[u]*w4.z; acc[u][3] += a0[u]*w4.w;
      }
    }
  }
  float4 bv = *(const float4*)&bias[t*128 + colq];
#pragma unroll
  for (int u = 0; u < 8; ++u) {
    int node = mt*64 + n8 + u;
    float4 o;
    o.x = acc[u][0] + bv.x; o.y = acc[u][1] + bv.y;
    o.z = acc[u][2] + bv.z; o.w = acc[u][3] + bv.w;
    if (z == 0) {
      int h = colq >> 4, d = colq & 15;
      *(float4*)&q_ws[((size_t)h*NB + node)*64 + t*16 + d] = o;
    } else {
      float* dst = (z == 1) ? kv_k : kv_v;
      *(float4*)&dst[(size_t)node*512 + t*128 + colq] = o;
    }
  }
}

// ---- K1b: kr/vr relation transform + zero agg & out slices. Grid (96, 8).
__global__ __launch_bounds__(256) void k1b_rel(
    const float* __restrict__ kv_k, const float* __restrict__ kv_v,
    const float* __restrict__ rel_att, const float* __restrict__ rel_msg,
    float* __restrict__ kr_ws, float* __restrict__ vr_ws,
    float* __restrict__ agg, float* __restrict__ out)
{
  __shared__ float ra_s[4][16][16];
  __shared__ float rm_s[4][16][16];
  __shared__ float k_s[16][4][17];
  __shared__ float v_s[16][4][17];
  int nb = blockIdx.x, h = blockIdx.y;
  int n0 = nb*16;
  int tid = threadIdx.x;
  // zero this block's agg + out slices (replaces memset; out needed for k5 atomics)
  agg[(size_t)(n0 + (tid >> 4))*128 + h*16 + (tid & 15)] = 0.f;
  out[(size_t)(n0 + (tid >> 4))*128 + h*16 + (tid & 15)] = 0.f;
#pragma unroll
  for (int u0 = 0; u0 < 4; ++u0) {
    int u = u0*256 + tid;
    int r = u >> 8, e = (u >> 4) & 15, d = u & 15;
    ra_s[r][e][d] = rel_att[((size_t)(r*8 + h)*16 + e)*16 + d];
    rm_s[r][e][d] = rel_msg[((size_t)(r*8 + h)*16 + e)*16 + d];
    int nl = u >> 6, s = (u >> 4) & 3, e2 = u & 15;
    k_s[nl][s][e2] = kv_k[(size_t)(n0 + nl)*512 + s*128 + h*16 + e2];
    v_s[nl][s][e2] = kv_v[(size_t)(n0 + nl)*512 + s*128 + h*16 + e2];
  }
  __syncthreads();
  int nl = tid >> 4, dq = tid & 15;
  size_t obase = ((size_t)h*NB + n0 + nl)*256;
#pragma unroll
  for (int r = 0; r < 4; ++r)
#pragma unroll
    for (int s = 0; s < 4; ++s) {
      float aK = 0.f, aV = 0.f;
#pragma unroll
      for (int e = 0; e < 16; ++e) {
        aK += k_s[nl][s][e] * ra_s[r][e][dq];
        aV += v_s[nl][s][e] * rm_s[r][e][dq];
      }
      kr_ws[obase + r*64 + s*16 + dq] = aK;
      vr_ws[obase + r*64 + s*16 + dq] = aV;
    }
}

// ---- K2: res_att[b,h,i,j] + per-tile column sums (fp32, precision-critical).
// Grid (72 = it*3+jseg, 8, 4). LDS diet: kr staged in two r-pair phases
// (kr_s 32x132 = 16.9 KB; block total ~21.8 KB -> 7 blocks/CU).
__global__ __launch_bounds__(256,2) void k2_att(
    const float* __restrict__ nt, const float* __restrict__ adj,
    const float* __restrict__ ets, const float* __restrict__ rel_pri,
    const float* __restrict__ q_ws, const float* __restrict__ kr_ws,
    float* __restrict__ res_att, float* __restrict__ att_part)
{
  __shared__ float q_s[16*68];
  __shared__ float kr_s[32*132];
  __shared__ float ntj_s[32*4];
  int bx = blockIdx.x, h = blockIdx.y, b = blockIdx.z;
  int it = bx / 3, jseg = bx % 3;
  int i0 = it*16;
  int tid = threadIdx.x;
  int j_l = tid>>3, ig = (tid>>1)&3, dh = tid&1;
  // stage q (identity copy, layout [i][t*16+d], row stride 68)
  {
    int i = tid>>4, f = (tid&15)*4;
    float4 qv = *(const float4*)&q_ws[((size_t)(h*NB) + b*Nn + i0 + i)*64 + f];
    *(float4*)&q_s[i*68 + f] = qv;
  }
  // nti in registers: ntiv[il][s]
  float ntiv[4][4];
#pragma unroll
  for (int il = 0; il < 4; ++il) {
    float4 v = *(const float4*)&nt[(size_t)(b*Nn + i0 + ig*4 + il)*TT];
    ntiv[il][0]=v.x; ntiv[il][1]=v.y; ntiv[il][2]=v.z; ntiv[il][3]=v.w;
  }
  float crr[4];
#pragma unroll
  for (int r = 0; r < 4; ++r) crr[r] = rel_pri[r*HH+h]*0.25f;

  int js = tid>>3, gb = tid&7;
  for (int jc = jseg*4; jc < jseg*4 + 4; ++jc) {
    __syncthreads();
    const float* src = &kr_ws[((size_t)(h*NB) + b*Nn + jc*32 + js)*256];
    // stage r-pair 0 (r = 0,1) + ntj
    {
      float* dst = &kr_s[js*132];
#pragma unroll
      for (int gl = 0; gl < 4; ++gl) {
        int g = gl*8 + gb;                 // granules 0..31 (r=0,1)
        *(float4*)&dst[g*4] = *(const float4*)&src[g*4];
      }
      if (tid < 128) ntj_s[tid] = nt[(size_t)(b*Nn + jc*32 + (tid>>2))*TT + (tid&3)];
    }
    __syncthreads();
    int j = jc*32 + j_l;
    float nt0 = ntj_s[j_l*4+0], nt1 = ntj_s[j_l*4+1];
    float nt2 = ntj_s[j_l*4+2], nt3 = ntj_s[j_l*4+3];
    // qn fold: 8 x ds_read_b128 per il on [t*16 + dh*8] windows
    float qn[4][8];
#pragma unroll
    for (int il = 0; il < 4; ++il) {
      const float* qb2 = &q_s[(ig*4 + il)*68 + dh*8];
      float4 a0 = *(const float4*)&qb2[0],  a1 = *(const float4*)&qb2[4];
      float4 b0 = *(const float4*)&qb2[16], b1 = *(const float4*)&qb2[20];
      float4 c0 = *(const float4*)&qb2[32], c1 = *(const float4*)&qb2[36];
      float4 d0v = *(const float4*)&qb2[48], d1v = *(const float4*)&qb2[52];
      qn[il][0] = a0.x*nt0 + b0.x*nt1 + c0.x*nt2 + d0v.x*nt3;
      qn[il][1] = a0.y*nt0 + b0.y*nt1 + c0.y*nt2 + d0v.y*nt3;
      qn[il][2] = a0.z*nt0 + b0.z*nt1 + c0.z*nt2 + d0v.z*nt3;
      qn[il][3] = a0.w*nt0 + b0.w*nt1 + c0.w*nt2 + d0v.w*nt3;
      qn[il][4] = a1.x*nt0 + b1.x*nt1 + c1.x*nt2 + d1v.x*nt3;
      qn[il][5] = a1.y*nt0 + b1.y*nt1 + c1.y*nt2 + d1v.y*nt3;
      qn[il][6] = a1.z*nt0 + b1.z*nt1 + c1.z*nt2 + d1v.z*nt3;
      qn[il][7] = a1.w*nt0 + b1.w*nt1 + c1.w*nt2 + d1v.w*nt3;
    }
    float mar[4][4];
#pragma unroll
    for (int il = 0; il < 4; ++il) {
      int i = i0 + ig*4 + il;
      float a = adj[((size_t)b*Nn + i)*Nn + j];
      float4 e4 = *(const float4*)&ets[(((size_t)b*Nn + i)*Nn + j)*RR];
      mar[il][0]=e4.x*a; mar[il][1]=e4.y*a; mar[il][2]=e4.z*a; mar[il][3]=e4.w*a;
    }
    float acc[4] = {0.f,0.f,0.f,0.f};
    const float* kbp = &kr_s[j_l*132 + dh*8];
    // compute r-pair 0
#pragma unroll
    for (int r = 0; r < 2; ++r) {
      float mr0 = mar[0][r]*crr[r], mr1 = mar[1][r]*crr[r];
      float mr2 = mar[2][r]*crr[r], mr3 = mar[3][r]*crr[r];
#pragma unroll
      for (int s = 0; s < 4; ++s) {
        float kk[8];
        *(float4*)&kk[0] = *(const float4*)&kbp[r*64 + s*16];
        *(float4*)&kk[4] = *(const float4*)&kbp[r*64 + s*16 + 4];
        float d0=0,d1=0,d2=0,d3=0;
#pragma unroll
        for (int dp = 0; dp < 8; ++dp) {
          d0 += qn[0][dp]*kk[dp]; d1 += qn[1][dp]*kk[dp];
          d2 += qn[2][dp]*kk[dp]; d3 += qn[3][dp]*kk[dp];
        }
        acc[0] += mr0*ntiv[0][s]*d0;
        acc[1] += mr1*ntiv[1][s]*d1;
        acc[2] += mr2*ntiv[2][s]*d2;
        acc[3] += mr3*ntiv[3][s]*d3;
      }
    }
    __syncthreads();
    // stage r-pair 1 (r = 2,3)
    {
      float* dst = &kr_s[js*132];
#pragma unroll
      for (int gl = 0; gl < 4; ++gl) {
        int g = gl*8 + gb;
        *(float4*)&dst[g*4] = *(const float4*)&src[128 + g*4];
      }
    }
    __syncthreads();
    // compute r-pair 1
#pragma unroll
    for (int r = 2; r < 4; ++r) {
      int rl = r - 2;
      float mr0 = mar[0][r]*crr[r], mr1 = mar[1][r]*crr[r];
      float mr2 = mar[2][r]*crr[r], mr3 = mar[3][r]*crr[r];
#pragma unroll
      for (int s = 0; s < 4; ++s) {
        float kk[8];
        *(float4*)&kk[0] = *(const float4*)&kbp[rl*64 + s*16];
        *(float4*)&kk[4] = *(const float4*)&kbp[rl*64 + s*16 + 4];
        float d0=0,d1=0,d2=0,d3=0;
#pragma unroll
        for (int dp = 0; dp < 8; ++dp) {
          d0 += qn[0][dp]*kk[dp]; d1 += qn[1][dp]*kk[dp];
          d2 += qn[2][dp]*kk[dp]; d3 += qn[3][dp]*kk[dp];
        }
        acc[0] += mr0*ntiv[0][s]*d0;
        acc[1] += mr1*ntiv[1][s]*d1;
        acc[2] += mr2*ntiv[2][s]*d2;
        acc[3] += mr3*ntiv[3][s]*d3;
      }
    }
    // combine dh halves (coefficients identical across the pair, sum distributes)
#pragma unroll
    for (int il = 0; il < 4; ++il)
      acc[il] += __shfl_xor(acc[il], 1);
    if (dh == 0) {
#pragma unroll
      for (int il = 0; il < 4; ++il)
        res_att[((size_t)(b*HH + h)*Nn + i0 + ig*4 + il)*Nn + j] = acc[il];
    }
    float v = acc[0] + acc[1] + acc[2] + acc[3];
    v += __shfl_xor(v, 2);
    v += __shfl_xor(v, 4);
    if ((tid & 7) == 0)
      att_part[(size_t)it*APART + (size_t)(b*HH + h)*Nn + j] = v;
  }
}

// ---- KC: MFMA message pass. Grid (it 6, jc 6, bh 32), 256 thr (4 waves).
// att_inv computed in-prologue from the 24 column partials. (round-12 version)
__global__ __launch_bounds__(256) void kc_agg(
    const float* __restrict__ nt, const float* __restrict__ adj,
    const float* __restrict__ ets, const float* __restrict__ rel_pri,
    const float* __restrict__ q_ws, const float* __restrict__ kr_ws,
    const float* __restrict__ vr_ws, const float* __restrict__ res_att,
    const float* __restrict__ att_part, float* __restrict__ agg)
{
  __shared__ __align__(16) unsigned short B_lds[4][64*72];
  __shared__ __align__(16) unsigned short vr_lds[64*72];
  __shared__ __align__(16) unsigned short Z_lds[4][16*72];
  __shared__ float ntj_s[256];
  __shared__ float inv_s[64];
  int it = blockIdx.x, jc = blockIdx.y, bh = blockIdx.z;
  int b = bh >> 3, h = bh & 7;
  int tid = threadIdx.x, w = tid >> 6, l = tid & 63;
  int j0 = jc*64;
  int ib = it*64 + w*16;
  int irow = ib + (l & 15);
  int iz = ib + ((l >> 4) << 2);
  int lq = (l >> 4) * 8;
  ntj_s[tid] = nt[(size_t)(b*Nn + j0 + (tid>>2))*4 + (tid&3)];
  if (tid < 64) {
    float s = 0.f;
#pragma unroll
    for (int p = 0; p < 24; ++p)
      s += att_part[(size_t)p*APART + (size_t)bh*Nn + j0 + tid];
    inv_s[tid] = (s > 1e-6f) ? 1.f/s : 0.f;
  }
  // A fragments: af[s][kk] = bf16(q[irow, k] * nti[irow, s])
  short8 af[4][2];
  {
    float q0[8], q1[8];
    const float* qp = &q_ws[((size_t)h*NB + b*Nn + irow)*64];
    *(float4*)&q0[0] = *(const float4*)&qp[lq];
    *(float4*)&q0[4] = *(const float4*)&qp[lq + 4];
    *(float4*)&q1[0] = *(const float4*)&qp[32 + lq];
    *(float4*)&q1[4] = *(const float4*)&qp[32 + lq + 4];
    float4 ntiv = *(const float4*)&nt[(size_t)(b*Nn + irow)*4];
    float nta[4] = {ntiv.x, ntiv.y, ntiv.z, ntiv.w};
#pragma unroll
    for (int s = 0; s < 4; ++s)
#pragma unroll
      for (int e = 0; e < 8; ++e) {
        af[s][0][e] = (short)f2bf(q0[e]*nta[s]);
        af[s][1][e] = (short)f2bf(q1[e]*nta[s]);
      }
  }
  float crv[4];
#pragma unroll
  for (int r = 0; r < 4; ++r) crv[r] = rel_pri[r*HH + h]*0.25f;
  // pre-barrier: cw0 = res_att*adj (global only); ets offsets
  float cw[4][4];
  int eo[4][4];
  const float* ebase = ets + (size_t)b*Nn*Nn*4;
#pragma unroll
  for (int tj = 0; tj < 4; ++tj) {
    int j = j0 + tj*16 + (l & 15);
#pragma unroll
    for (int p = 0; p < 4; ++p) {
      int i = iz + p;
      cw[tj][p] = res_att[((size_t)bh*Nn + i)*Nn + j]
                * adj[((size_t)b*Nn + i)*Nn + j];
      eo[tj][p] = (i*Nn + j)*4;
    }
  }
  f32x4 agg_acc = {0.f,0.f,0.f,0.f};
  // coalesced staging assignment: thread = (js 64, ss 4)
  int js = tid >> 2, ss = tid & 3;
  const float* krp = &kr_ws[((size_t)h*NB + b*Nn + j0 + js)*256 + ss*16];
  const float* vrp = &vr_ws[((size_t)h*NB + b*Nn + j0 + js)*256 + ss*16];
  float kvA[16], vvA[16];
  ld16(krp, kvA);
  ld16(vrp, vvA);
  bar_lds();   // ntj_s + inv_s visible
  // finish cw with inv
#pragma unroll
  for (int tj = 0; tj < 4; ++tj) {
    float inv = inv_s[tj*16 + (l & 15)];
#pragma unroll
    for (int p = 0; p < 4; ++p) cw[tj][p] *= inv;
  }

#pragma unroll
  for (int r = 0; r < 4; ++r) {
    if (r) bar_lds();   // previous compute's LDS reads done before overwrite
    // STAGE r (B scaled by ntj*crv[r]; vr transposed)
    {
      float crr = crv[r];
      float4 ntjv = *(const float4*)&ntj_s[js*4];
      float nta[4] = {ntjv.x*crr, ntjv.y*crr, ntjv.z*crr, ntjv.w*crr};
#pragma unroll
      for (int t = 0; t < 4; ++t) {
#pragma unroll
        for (int dq = 0; dq < 2; ++dq) {
          short8 v;
#pragma unroll
          for (int e = 0; e < 8; ++e) v[e] = (short)f2bf(kvA[dq*8 + e]*nta[t]);
          *(short8*)&B_lds[ss][js*72 + t*16 + dq*8] = v;
        }
      }
#pragma unroll
      for (int d = 0; d < 16; ++d)
        vr_lds[(ss*16 + d)*72 + js] = f2bf(vvA[d]);
    }
    // prefetch r+1 into registers (stays in flight across barrier)
    float kvB[16], vvB[16];
    if (r < 3) {
      ld16(krp + (r+1)*64, kvB);
      ld16(vrp + (r+1)*64, vvB);
    }
    bar_lds();
    // COMPUTE r
    float coef[4][4];
#pragma unroll
    for (int tj = 0; tj < 4; ++tj)
#pragma unroll
      for (int p = 0; p < 4; ++p)
        coef[tj][p] = ebase[eo[tj][p] + r] * cw[tj][p];
#pragma unroll
    for (int s = 0; s < 4; ++s) {
      f32x4 wacc[4];
#pragma unroll
      for (int tj = 0; tj < 4; ++tj) wacc[tj] = (f32x4){0.f,0.f,0.f,0.f};
#pragma unroll
      for (int tj = 0; tj < 4; ++tj) {
        short8 b0 = *(const short8*)&B_lds[s][(tj*16 + (l & 15))*72 + lq];
        short8 b1 = *(const short8*)&B_lds[s][(tj*16 + (l & 15))*72 + 32 + lq];
        wacc[tj] = __builtin_amdgcn_mfma_f32_16x16x32_bf16(af[s][0], b0, wacc[tj], 0, 0, 0);
        wacc[tj] = __builtin_amdgcn_mfma_f32_16x16x32_bf16(af[s][1], b1, wacc[tj], 0, 0, 0);
      }
#pragma unroll
      for (int tj = 0; tj < 4; ++tj)
#pragma unroll
        for (int p = 0; p < 4; ++p)
          Z_lds[w][(((l >> 4)*4) + p)*72 + tj*16 + (l & 15)] = f2bf(wacc[tj][p]*coef[tj][p]);
#pragma unroll
      for (int kj = 0; kj < 2; ++kj) {
        short8 zf = *(const short8*)&Z_lds[w][(l & 15)*72 + kj*32 + lq];
        short8 vf = *(const short8*)&vr_lds[(s*16 + (l & 15))*72 + kj*32 + lq];
        agg_acc = __builtin_amdgcn_mfma_f32_16x16x32_bf16(zf, vf, agg_acc, 0, 0, 0);
      }
    }
    if (r < 3) {
#pragma unroll
      for (int e = 0; e < 16; ++e) { kvA[e] = kvB[e]; vvA[e] = vvB[e]; }
    }
  }
#pragma unroll
  for (int p = 0; p < 4; ++p)
    atomicAdd(&agg[((size_t)b*Nn + iz + p)*128 + h*16 + (l & 15)], agg_acc[p]);
}

// K5: trans = agg.aw + ab, GELU, skip-gate, LayerNorm, type-mix.
// Grid (384 node-quads, 4 t), 128 thr = (group g 4 nodes, o-quad 32).
__global__ __launch_bounds__(128) void k5_out(
    const float* __restrict__ agg_ws, const float* __restrict__ nf,
    const float* __restrict__ nt, const float* __restrict__ aw,
    const float* __restrict__ ab, const float* __restrict__ norm_w,
    const float* __restrict__ norm_b, const float* __restrict__ skip,
    float* __restrict__ out)
{
  __shared__ float agg_s[4][128];
  int nq = blockIdx.x, t = blockIdx.y;
  int tid = threadIdx.x;
  int g = tid >> 5, o0 = (tid & 31)*4;
  {
    int nl = tid >> 5, c = (tid & 31)*4;
    *(float4*)&agg_s[nl][c] = *(const float4*)&agg_ws[(size_t)(nq*4 + nl)*128 + c];
  }
  __syncthreads();
  size_t node = (size_t)nq*4 + g;
  float alpha = 1.f/(1.f + expf(-skip[t]));
  float4 bv = *(const float4*)&ab[t*128 + o0];
  float a0 = bv.x, a1 = bv.y, a2 = bv.z, a3 = bv.w;
  const float* awt = aw + (size_t)t*128*128;
  for (int dd = 0; dd < 128; ++dd) {
    float av = agg_s[g][dd];
    float4 wv = *(const float4*)&awt[dd*128 + o0];
    a0 += av*wv.x; a1 += av*wv.y; a2 += av*wv.z; a3 += av*wv.w;
  }
  float4 nfv = *(const float4*)&nf[node*128 + o0];
  float av4[4] = {a0, a1, a2, a3};
  float nfa[4] = {nfv.x, nfv.y, nfv.z, nfv.w};
  float res[4];
#pragma unroll
  for (int c = 0; c < 4; ++c) {
    float gl = 0.5f*av4[c]*(1.f + erff(av4[c]*0.70710678118654752f));
    res[c] = gl*alpha + nfa[c]*(1.f - alpha);
  }
  float s1 = res[0]+res[1]+res[2]+res[3];
  float s2 = res[0]*res[0]+res[1]*res[1]+res[2]*res[2]+res[3]*res[3];
#pragma unroll
  for (int m = 16; m >= 1; m >>= 1) { s1 += __shfl_xor(s1, m); s2 += __shfl_xor(s2, m); }
  float mean = s1*(1.f/128.f);
  float var  = s2*(1.f/128.f) - mean*mean;
  float rstd = rsqrtf(var + 1e-5f);
  float ntv = nt[node*TT + t];
  float4 nwv = *(const float4*)&norm_w[t*128 + o0];
  float4 nbv = *(const float4*)&norm_b[t*128 + o0];
  float nww[4] = {nwv.x, nwv.y, nwv.z, nwv.w};
  float nbb[4] = {nbv.x, nbv.y, nbv.z, nbv.w};
#pragma unroll
  for (int c = 0; c < 4; ++c) {
    float nrm = (res[c] - mean)*rstd*nww[c] + nbb[c];
    atomicAdd(&out[node*128 + o0 + c], nrm*ntv);
  }
}

extern "C" void kernel_launch(void* const* d_in, const int* in_sizes, int n_in,
                              void* d_out, int out_size, void* d_ws, size_t ws_size,
                              hipStream_t stream) {
  const float* nf      = (const float*)d_in[0];
  const float* nts     = (const float*)d_in[1];
  const float* adj     = (const float*)d_in[2];
  const float* ets     = (const float*)d_in[3];
  const float* kw      = (const float*)d_in[4];
  const float* kb      = (const float*)d_in[5];
  const float* qw      = (const float*)d_in[6];
  const float* qb      = (const float*)d_in[7];
  const float* vw      = (const float*)d_in[8];
  const float* vb      = (const float*)d_in[9];
  const float* aw      = (const float*)d_in[10];
  const float* ab      = (const float*)d_in[11];
  const float* normw   = (const float*)d_in[12];
  const float* normb   = (const float*)d_in[13];
  const float* rel_pri = (const float*)d_in[14];
  const float* rel_att = (const float*)d_in[15];
  const float* rel_msg = (const float*)d_in[16];
  const float* skip    = (const float*)d_in[17];
  (void)in_sizes; (void)n_in; (void)out_size; (void)ws_size;

  float* ws = (float*)d_ws;
  float* q_ws    = ws;                        // 786432
  float* kr_ws   = q_ws + 786432;             // 3145728
  float* vr_ws   = kr_ws + 3145728;           // 3145728
  float* res_att = vr_ws + 3145728;           // 4718592
  float* att_part= res_att + 4718592;         // 294912 (24 x 12288)
  float* agg_ws  = att_part + 294912 + 12288; // 196608
  // kv scratch aliases res_att (dead until k2 writes it)
  float* kv_k = res_att;                      // 786432
  float* kv_v = res_att + 786432;             // 786432

  hipLaunchKernelGGL(k1a_qkv, dim3(24, 4, 3), dim3(256), 0, stream,
                     nf, qw, qb, kw, kb, vw, vb, q_ws, kv_k, kv_v);
  hipLaunchKernelGGL(k1b_rel, dim3(96, 8), dim3(256), 0, stream,
                     kv_k, kv_v, rel_att, rel_msg, kr_ws, vr_ws, agg_ws, (float*)d_out);
  hipLaunchKernelGGL(k2_att, dim3(72, 8, 4), dim3(256), 0, stream,
                     nts, adj, ets, rel_pri, q_ws, kr_ws, res_att, att_part);
  hipLaunchKernelGGL(kc_agg, dim3(6, 6, 32), dim3(256), 0, stream,
                     nts, adj, ets, rel_pri, q_ws, kr_ws, vr_ws, res_att, att_part, agg_ws);
  hipLaunchKernelGGL(k5_out, dim3(384, 4), dim3(128), 0, stream,
                     agg_ws, nf, nts, aw, ab, normw, normb, skip, (float*)d_out);
}

// Round 15
// 184.032 us; speedup vs baseline: 1.1545x; 1.0724x over previous
//
#include <hip/hip_runtime.h>
#include <math.h>

#define Bq 4
#define Nn 384
#define NB 1536   // Bq*Nn
#define TT 4
#define RR 4
#define HH 8
#define DKk 16
#define APART 12288   // att_part stride per i-tile: 32 bh * 384 j

typedef __attribute__((ext_vector_type(8))) short short8;
typedef __attribute__((ext_vector_type(4))) float f32x4;

__device__ __forceinline__ unsigned short f2bf(float f) {
  unsigned u = __float_as_uint(f);
  u += 0x7FFFu + ((u >> 16) & 1u);
  return (unsigned short)(u >> 16);
}

__device__ __forceinline__ void ld16(const float* __restrict__ p, float* o) {
  const float4* p4 = reinterpret_cast<const float4*>(p);
  float4 a = p4[0], b = p4[1], c = p4[2], d = p4[3];
  o[0]=a.x; o[1]=a.y; o[2]=a.z; o[3]=a.w;
  o[4]=b.x; o[5]=b.y; o[6]=b.z; o[7]=b.w;
  o[8]=c.x; o[9]=c.y; o[10]=c.z; o[11]=c.w;
  o[12]=d.x; o[13]=d.y; o[14]=d.z; o[15]=d.w;
}

// barrier that waits only LDS ops (lgkmcnt) — leaves register-destined global
// loads (vmcnt) in flight across the barrier (prefetch survives).
__device__ __forceinline__ void bar_lds() {
  asm volatile("s_waitcnt lgkmcnt(0)" ::: "memory");
  __builtin_amdgcn_s_barrier();
}

// layouts:
//  q_ws : [h][node][t*16+d]          64 f per (h,node)
//  kr_ws/vr_ws: [h][node][r*64+s*16+d]   256 f per (h,node)
//  kv_k/kv_v (aliases res_att, dead until k2): [node][t*128+c]
//  res_att: [b][h][i][j];  att_part: [it 24][bh][j]
//  agg  : [node][h*16+d]   (zeroed by k1b);  out zeroed by k1b too

// ---- K1a: QKV projection GEMM. Grid (24 node-tiles, 4 t, 3 proj), 256 thr.
__global__ __launch_bounds__(256) void k1a_qkv(
    const float* __restrict__ nf,
    const float* __restrict__ qw, const float* __restrict__ qb,
    const float* __restrict__ kw, const float* __restrict__ kb,
    const float* __restrict__ vw, const float* __restrict__ vb,
    float* __restrict__ q_ws, float* __restrict__ kv_k, float* __restrict__ kv_v)
{
  __shared__ float A_s[32][72];    // [k][node]
  __shared__ float W_s[32][132];   // [k][col]
  int mt = blockIdx.x, t = blockIdx.y, z = blockIdx.z;
  const float* W    = (z == 0) ? qw : ((z == 1) ? kw : vw);
  const float* bias = (z == 0) ? qb : ((z == 1) ? kb : vb);
  int tid = threadIdx.x;
  int colq = (tid & 31)*4, n8 = (tid >> 5)*8;
  float acc[8][4];
#pragma unroll
  for (int u = 0; u < 8; ++u)
#pragma unroll
    for (int c = 0; c < 4; ++c) acc[u][c] = 0.f;

  for (int kc = 0; kc < 4; ++kc) {
    __syncthreads();
    {
      int kk = tid & 31, nb0 = tid >> 5;
#pragma unroll
      for (int u = 0; u < 8; ++u)
        A_s[kk][nb0 + u*8] = nf[(size_t)(mt*64 + nb0 + u*8)*128 + kc*32 + kk];
#pragma unroll
      for (int u = 0; u < 4; ++u) {
        int idx = u*256 + tid;
        int wk = idx >> 5, c4 = (idx & 31)*4;
        *(float4*)&W_s[wk][c4] = *(const float4*)&W[(size_t)(t*128 + kc*32 + wk)*128 + c4];
      }
    }
    __syncthreads();
#pragma unroll
    for (int k = 0; k < 32; ++k) {
      float4 w4 = *(float4*)&W_s[k][colq];
      float a0[8];
      *(float4*)&a0[0] = *(float4*)&A_s[k][n8];
      *(float4*)&a0[4] = *(float4*)&A_s[k][n8 + 4];
#pragma unroll
      for (int u = 0; u < 8; ++u) {
        acc[u][0] += a0[u]*w4.x; acc[u][1] += a0[u]*w4.y;
        acc[u][2] += a0[u]*w4.z; acc[u][3] += a0[u]*w4.w;
      }
    }
  }
  float4 bv = *(const float4*)&bias[t*128 + colq];
#pragma unroll
  for (int u = 0; u < 8; ++u) {
    int node = mt*64 + n8 + u;
    float4 o;
    o.x = acc[u][0] + bv.x; o.y = acc[u][1] + bv.y;
    o.z = acc[u][2] + bv.z; o.w = acc[u][3] + bv.w;
    if (z == 0) {
      int h = colq >> 4, d = colq & 15;
      *(float4*)&q_ws[((size_t)h*NB + node)*64 + t*16 + d] = o;
    } else {
      float* dst = (z == 1) ? kv_k : kv_v;
      *(float4*)&dst[(size_t)node*512 + t*128 + colq] = o;
    }
  }
}

// ---- K1b: kr/vr relation transform + zero agg & out slices. Grid (96, 8).
__global__ __launch_bounds__(256) void k1b_rel(
    const float* __restrict__ kv_k, const float* __restrict__ kv_v,
    const float* __restrict__ rel_att, const float* __restrict__ rel_msg,
    float* __restrict__ kr_ws, float* __restrict__ vr_ws,
    float* __restrict__ agg, float* __restrict__ out)
{
  __shared__ float ra_s[4][16][16];
  __shared__ float rm_s[4][16][16];
  __shared__ float k_s[16][4][17];
  __shared__ float v_s[16][4][17];
  int nb = blockIdx.x, h = blockIdx.y;
  int n0 = nb*16;
  int tid = threadIdx.x;
  // zero this block's agg + out slices (replaces memset; out needed for k5 atomics)
  agg[(size_t)(n0 + (tid >> 4))*128 + h*16 + (tid & 15)] = 0.f;
  out[(size_t)(n0 + (tid >> 4))*128 + h*16 + (tid & 15)] = 0.f;
#pragma unroll
  for (int u0 = 0; u0 < 4; ++u0) {
    int u = u0*256 + tid;
    int r = u >> 8, e = (u >> 4) & 15, d = u & 15;
    ra_s[r][e][d] = rel_att[((size_t)(r*8 + h)*16 + e)*16 + d];
    rm_s[r][e][d] = rel_msg[((size_t)(r*8 + h)*16 + e)*16 + d];
    int nl = u >> 6, s = (u >> 4) & 3, e2 = u & 15;
    k_s[nl][s][e2] = kv_k[(size_t)(n0 + nl)*512 + s*128 + h*16 + e2];
    v_s[nl][s][e2] = kv_v[(size_t)(n0 + nl)*512 + s*128 + h*16 + e2];
  }
  __syncthreads();
  int nl = tid >> 4, dq = tid & 15;
  size_t obase = ((size_t)h*NB + n0 + nl)*256;
#pragma unroll
  for (int r = 0; r < 4; ++r)
#pragma unroll
    for (int s = 0; s < 4; ++s) {
      float aK = 0.f, aV = 0.f;
#pragma unroll
      for (int e = 0; e < 16; ++e) {
        aK += k_s[nl][s][e] * ra_s[r][e][dq];
        aV += v_s[nl][s][e] * rm_s[r][e][dq];
      }
      kr_ws[obase + r*64 + s*16 + dq] = aK;
      vr_ws[obase + r*64 + s*16 + dq] = aV;
    }
}

// ---- K2: res_att[b,h,i,j] + per-tile column sums (fp32, precision-critical).
// Round-12 proven version: grid (48 = it*2+jh, 8, 4), identity kr staging,
// b128 qn fold, nti in registers, deferred dh-shuffle.
__global__ __launch_bounds__(256,2) void k2_att(
    const float* __restrict__ nt, const float* __restrict__ adj,
    const float* __restrict__ ets, const float* __restrict__ rel_pri,
    const float* __restrict__ q_ws, const float* __restrict__ kr_ws,
    float* __restrict__ res_att, float* __restrict__ att_part)
{
  __shared__ float q_s[16*68];
  __shared__ float kr_s[32*260];
  __shared__ float ntj_s[32*4];
  int bx = blockIdx.x, h = blockIdx.y, b = blockIdx.z;
  int it = bx >> 1, jh = bx & 1;
  int i0 = it*16;
  int tid = threadIdx.x;
  int j_l = tid>>3, ig = (tid>>1)&3, dh = tid&1;
  // stage q (identity copy, layout [i][t*16+d], row stride 68)
  {
    int i = tid>>4, f = (tid&15)*4;
    float4 qv = *(const float4*)&q_ws[((size_t)(h*NB) + b*Nn + i0 + i)*64 + f];
    *(float4*)&q_s[i*68 + f] = qv;
  }
  // nti in registers: ntiv[il][s]
  float ntiv[4][4];
#pragma unroll
  for (int il = 0; il < 4; ++il) {
    float4 v = *(const float4*)&nt[(size_t)(b*Nn + i0 + ig*4 + il)*TT];
    ntiv[il][0]=v.x; ntiv[il][1]=v.y; ntiv[il][2]=v.z; ntiv[il][3]=v.w;
  }
  float crr[4];
#pragma unroll
  for (int r = 0; r < 4; ++r) crr[r] = rel_pri[r*HH+h]*0.25f;

  for (int jc = jh*6; jc < jh*6 + 6; ++jc) {
    __syncthreads();
    {
      int js = tid>>3, gb = tid&7;
      const float* src = &kr_ws[((size_t)(h*NB) + b*Nn + jc*32 + js)*256];
      float* dst = &kr_s[js*260];
#pragma unroll
      for (int gl = 0; gl < 8; ++gl) {
        int g = gl*8 + gb;
        *(float4*)&dst[g*4] = *(const float4*)&src[g*4];
      }
      if (tid < 128) ntj_s[tid] = nt[(size_t)(b*Nn + jc*32 + (tid>>2))*TT + (tid&3)];
    }
    __syncthreads();
    int j = jc*32 + j_l;
    float nt0 = ntj_s[j_l*4+0], nt1 = ntj_s[j_l*4+1];
    float nt2 = ntj_s[j_l*4+2], nt3 = ntj_s[j_l*4+3];
    // qn fold: 8 x ds_read_b128 per il on [t*16 + dh*8] windows
    float qn[4][8];
#pragma unroll
    for (int il = 0; il < 4; ++il) {
      const float* qb2 = &q_s[(ig*4 + il)*68 + dh*8];
      float4 a0 = *(const float4*)&qb2[0],  a1 = *(const float4*)&qb2[4];
      float4 b0 = *(const float4*)&qb2[16], b1 = *(const float4*)&qb2[20];
      float4 c0 = *(const float4*)&qb2[32], c1 = *(const float4*)&qb2[36];
      float4 d0v = *(const float4*)&qb2[48], d1v = *(const float4*)&qb2[52];
      qn[il][0] = a0.x*nt0 + b0.x*nt1 + c0.x*nt2 + d0v.x*nt3;
      qn[il][1] = a0.y*nt0 + b0.y*nt1 + c0.y*nt2 + d0v.y*nt3;
      qn[il][2] = a0.z*nt0 + b0.z*nt1 + c0.z*nt2 + d0v.z*nt3;
      qn[il][3] = a0.w*nt0 + b0.w*nt1 + c0.w*nt2 + d0v.w*nt3;
      qn[il][4] = a1.x*nt0 + b1.x*nt1 + c1.x*nt2 + d1v.x*nt3;
      qn[il][5] = a1.y*nt0 + b1.y*nt1 + c1.y*nt2 + d1v.y*nt3;
      qn[il][6] = a1.z*nt0 + b1.z*nt1 + c1.z*nt2 + d1v.z*nt3;
      qn[il][7] = a1.w*nt0 + b1.w*nt1 + c1.w*nt2 + d1v.w*nt3;
    }
    float mar[4][4];
#pragma unroll
    for (int il = 0; il < 4; ++il) {
      int i = i0 + ig*4 + il;
      float a = adj[((size_t)b*Nn + i)*Nn + j];
      float4 e4 = *(const float4*)&ets[(((size_t)b*Nn + i)*Nn + j)*RR];
      mar[il][0]=e4.x*a; mar[il][1]=e4.y*a; mar[il][2]=e4.z*a; mar[il][3]=e4.w*a;
    }
    float acc[4] = {0.f,0.f,0.f,0.f};
    const float* kbp = &kr_s[j_l*260 + dh*8];
#pragma unroll
    for (int r = 0; r < 4; ++r) {
      float mr0 = mar[0][r]*crr[r], mr1 = mar[1][r]*crr[r];
      float mr2 = mar[2][r]*crr[r], mr3 = mar[3][r]*crr[r];
#pragma unroll
      for (int s = 0; s < 4; ++s) {
        float kk[8];
        *(float4*)&kk[0] = *(const float4*)&kbp[r*64 + s*16];
        *(float4*)&kk[4] = *(const float4*)&kbp[r*64 + s*16 + 4];
        float d0=0,d1=0,d2=0,d3=0;
#pragma unroll
        for (int dp = 0; dp < 8; ++dp) {
          d0 += qn[0][dp]*kk[dp]; d1 += qn[1][dp]*kk[dp];
          d2 += qn[2][dp]*kk[dp]; d3 += qn[3][dp]*kk[dp];
        }
        acc[0] += mr0*ntiv[0][s]*d0;
        acc[1] += mr1*ntiv[1][s]*d1;
        acc[2] += mr2*ntiv[2][s]*d2;
        acc[3] += mr3*ntiv[3][s]*d3;
      }
    }
    // combine dh halves (coefficients identical across the pair, sum distributes)
#pragma unroll
    for (int il = 0; il < 4; ++il)
      acc[il] += __shfl_xor(acc[il], 1);
    if (dh == 0) {
#pragma unroll
      for (int il = 0; il < 4; ++il)
        res_att[((size_t)(b*HH + h)*Nn + i0 + ig*4 + il)*Nn + j] = acc[il];
    }
    float v = acc[0] + acc[1] + acc[2] + acc[3];
    v += __shfl_xor(v, 2);
    v += __shfl_xor(v, 4);
    if ((tid & 7) == 0)
      att_part[(size_t)it*APART + (size_t)(b*HH + h)*Nn + j] = v;
  }
}

// ---- KC: MFMA message pass. Grid (it 6, jc 6, bh 32), 256 thr (4 waves).
// att_inv computed in-prologue from the 24 column partials. (round-12 version)
__global__ __launch_bounds__(256) void kc_agg(
    const float* __restrict__ nt, const float* __restrict__ adj,
    const float* __restrict__ ets, const float* __restrict__ rel_pri,
    const float* __restrict__ q_ws, const float* __restrict__ kr_ws,
    const float* __restrict__ vr_ws, const float* __restrict__ res_att,
    const float* __restrict__ att_part, float* __restrict__ agg)
{
  __shared__ __align__(16) unsigned short B_lds[4][64*72];
  __shared__ __align__(16) unsigned short vr_lds[64*72];
  __shared__ __align__(16) unsigned short Z_lds[4][16*72];
  __shared__ float ntj_s[256];
  __shared__ float inv_s[64];
  int it = blockIdx.x, jc = blockIdx.y, bh = blockIdx.z;
  int b = bh >> 3, h = bh & 7;
  int tid = threadIdx.x, w = tid >> 6, l = tid & 63;
  int j0 = jc*64;
  int ib = it*64 + w*16;
  int irow = ib + (l & 15);
  int iz = ib + ((l >> 4) << 2);
  int lq = (l >> 4) * 8;
  ntj_s[tid] = nt[(size_t)(b*Nn + j0 + (tid>>2))*4 + (tid&3)];
  if (tid < 64) {
    float s = 0.f;
#pragma unroll
    for (int p = 0; p < 24; ++p)
      s += att_part[(size_t)p*APART + (size_t)bh*Nn + j0 + tid];
    inv_s[tid] = (s > 1e-6f) ? 1.f/s : 0.f;
  }
  // A fragments: af[s][kk] = bf16(q[irow, k] * nti[irow, s])
  short8 af[4][2];
  {
    float q0[8], q1[8];
    const float* qp = &q_ws[((size_t)h*NB + b*Nn + irow)*64];
    *(float4*)&q0[0] = *(const float4*)&qp[lq];
    *(float4*)&q0[4] = *(const float4*)&qp[lq + 4];
    *(float4*)&q1[0] = *(const float4*)&qp[32 + lq];
    *(float4*)&q1[4] = *(const float4*)&qp[32 + lq + 4];
    float4 ntiv = *(const float4*)&nt[(size_t)(b*Nn + irow)*4];
    float nta[4] = {ntiv.x, ntiv.y, ntiv.z, ntiv.w};
#pragma unroll
    for (int s = 0; s < 4; ++s)
#pragma unroll
      for (int e = 0; e < 8; ++e) {
        af[s][0][e] = (short)f2bf(q0[e]*nta[s]);
        af[s][1][e] = (short)f2bf(q1[e]*nta[s]);
      }
  }
  float crv[4];
#pragma unroll
  for (int r = 0; r < 4; ++r) crv[r] = rel_pri[r*HH + h]*0.25f;
  // pre-barrier: cw0 = res_att*adj (global only); ets offsets
  float cw[4][4];
  int eo[4][4];
  const float* ebase = ets + (size_t)b*Nn*Nn*4;
#pragma unroll
  for (int tj = 0; tj < 4; ++tj) {
    int j = j0 + tj*16 + (l & 15);
#pragma unroll
    for (int p = 0; p < 4; ++p) {
      int i = iz + p;
      cw[tj][p] = res_att[((size_t)bh*Nn + i)*Nn + j]
                * adj[((size_t)b*Nn + i)*Nn + j];
      eo[tj][p] = (i*Nn + j)*4;
    }
  }
  f32x4 agg_acc = {0.f,0.f,0.f,0.f};
  // coalesced staging assignment: thread = (js 64, ss 4)
  int js = tid >> 2, ss = tid & 3;
  const float* krp = &kr_ws[((size_t)h*NB + b*Nn + j0 + js)*256 + ss*16];
  const float* vrp = &vr_ws[((size_t)h*NB + b*Nn + j0 + js)*256 + ss*16];
  float kvA[16], vvA[16];
  ld16(krp, kvA);
  ld16(vrp, vvA);
  bar_lds();   // ntj_s + inv_s visible
  // finish cw with inv
#pragma unroll
  for (int tj = 0; tj < 4; ++tj) {
    float inv = inv_s[tj*16 + (l & 15)];
#pragma unroll
    for (int p = 0; p < 4; ++p) cw[tj][p] *= inv;
  }

#pragma unroll
  for (int r = 0; r < 4; ++r) {
    if (r) bar_lds();   // previous compute's LDS reads done before overwrite
    // STAGE r (B scaled by ntj*crv[r]; vr transposed)
    {
      float crr = crv[r];
      float4 ntjv = *(const float4*)&ntj_s[js*4];
      float nta[4] = {ntjv.x*crr, ntjv.y*crr, ntjv.z*crr, ntjv.w*crr};
#pragma unroll
      for (int t = 0; t < 4; ++t) {
#pragma unroll
        for (int dq = 0; dq < 2; ++dq) {
          short8 v;
#pragma unroll
          for (int e = 0; e < 8; ++e) v[e] = (short)f2bf(kvA[dq*8 + e]*nta[t]);
          *(short8*)&B_lds[ss][js*72 + t*16 + dq*8] = v;
        }
      }
#pragma unroll
      for (int d = 0; d < 16; ++d)
        vr_lds[(ss*16 + d)*72 + js] = f2bf(vvA[d]);
    }
    // prefetch r+1 into registers (stays in flight across barrier)
    float kvB[16], vvB[16];
    if (r < 3) {
      ld16(krp + (r+1)*64, kvB);
      ld16(vrp + (r+1)*64, vvB);
    }
    bar_lds();
    // COMPUTE r
    float coef[4][4];
#pragma unroll
    for (int tj = 0; tj < 4; ++tj)
#pragma unroll
      for (int p = 0; p < 4; ++p)
        coef[tj][p] = ebase[eo[tj][p] + r] * cw[tj][p];
#pragma unroll
    for (int s = 0; s < 4; ++s) {
      f32x4 wacc[4];
#pragma unroll
      for (int tj = 0; tj < 4; ++tj) wacc[tj] = (f32x4){0.f,0.f,0.f,0.f};
#pragma unroll
      for (int tj = 0; tj < 4; ++tj) {
        short8 b0 = *(const short8*)&B_lds[s][(tj*16 + (l & 15))*72 + lq];
        short8 b1 = *(const short8*)&B_lds[s][(tj*16 + (l & 15))*72 + 32 + lq];
        wacc[tj] = __builtin_amdgcn_mfma_f32_16x16x32_bf16(af[s][0], b0, wacc[tj], 0, 0, 0);
        wacc[tj] = __builtin_amdgcn_mfma_f32_16x16x32_bf16(af[s][1], b1, wacc[tj], 0, 0, 0);
      }
#pragma unroll
      for (int tj = 0; tj < 4; ++tj)
#pragma unroll
        for (int p = 0; p < 4; ++p)
          Z_lds[w][(((l >> 4)*4) + p)*72 + tj*16 + (l & 15)] = f2bf(wacc[tj][p]*coef[tj][p]);
#pragma unroll
      for (int kj = 0; kj < 2; ++kj) {
        short8 zf = *(const short8*)&Z_lds[w][(l & 15)*72 + kj*32 + lq];
        short8 vf = *(const short8*)&vr_lds[(s*16 + (l & 15))*72 + kj*32 + lq];
        agg_acc = __builtin_amdgcn_mfma_f32_16x16x32_bf16(zf, vf, agg_acc, 0, 0, 0);
      }
    }
    if (r < 3) {
#pragma unroll
      for (int e = 0; e < 16; ++e) { kvA[e] = kvB[e]; vvA[e] = vvB[e]; }
    }
  }
#pragma unroll
  for (int p = 0; p < 4; ++p)
    atomicAdd(&agg[((size_t)b*Nn + iz + p)*128 + h*16 + (l & 15)], agg_acc[p]);
}

// K5: trans = agg.aw + ab, GELU, skip-gate, LayerNorm, type-mix.
// Grid (384 node-quads, 4 t), 128 thr = (group g 4 nodes, o-quad 32).
__global__ __launch_bounds__(128) void k5_out(
    const float* __restrict__ agg_ws, const float* __restrict__ nf,
    const float* __restrict__ nt, const float* __restrict__ aw,
    const float* __restrict__ ab, const float* __restrict__ norm_w,
    const float* __restrict__ norm_b, const float* __restrict__ skip,
    float* __restrict__ out)
{
  __shared__ float agg_s[4][128];
  int nq = blockIdx.x, t = blockIdx.y;
  int tid = threadIdx.x;
  int g = tid >> 5, o0 = (tid & 31)*4;
  {
    int nl = tid >> 5, c = (tid & 31)*4;
    *(float4*)&agg_s[nl][c] = *(const float4*)&agg_ws[(size_t)(nq*4 + nl)*128 + c];
  }
  __syncthreads();
  size_t node = (size_t)nq*4 + g;
  float alpha = 1.f/(1.f + expf(-skip[t]));
  float4 bv = *(const float4*)&ab[t*128 + o0];
  float a0 = bv.x, a1 = bv.y, a2 = bv.z, a3 = bv.w;
  const float* awt = aw + (size_t)t*128*128;
  for (int dd = 0; dd < 128; ++dd) {
    float av = agg_s[g][dd];
    float4 wv = *(const float4*)&awt[dd*128 + o0];
    a0 += av*wv.x; a1 += av*wv.y; a2 += av*wv.z; a3 += av*wv.w;
  }
  float4 nfv = *(const float4*)&nf[node*128 + o0];
  float av4[4] = {a0, a1, a2, a3};
  float nfa[4] = {nfv.x, nfv.y, nfv.z, nfv.w};
  float res[4];
#pragma unroll
  for (int c = 0; c < 4; ++c) {
    float gl = 0.5f*av4[c]*(1.f + erff(av4[c]*0.70710678118654752f));
    res[c] = gl*alpha + nfa[c]*(1.f - alpha);
  }
  float s1 = res[0]+res[1]+res[2]+res[3];
  float s2 = res[0]*res[0]+res[1]*res[1]+res[2]*res[2]+res[3]*res[3];
#pragma unroll
  for (int m = 16; m >= 1; m >>= 1) { s1 += __shfl_xor(s1, m); s2 += __shfl_xor(s2, m); }
  float mean = s1*(1.f/128.f);
  float var  = s2*(1.f/128.f) - mean*mean;
  float rstd = rsqrtf(var + 1e-5f);
  float ntv = nt[node*TT + t];
  float4 nwv = *(const float4*)&norm_w[t*128 + o0];
  float4 nbv = *(const float4*)&norm_b[t*128 + o0];
  float nww[4] = {nwv.x, nwv.y, nwv.z, nwv.w};
  float nbb[4] = {nbv.x, nbv.y, nbv.z, nbv.w};
#pragma unroll
  for (int c = 0; c < 4; ++c) {
    float nrm = (res[c] - mean)*rstd*nww[c] + nbb[c];
    atomicAdd(&out[node*128 + o0 + c], nrm*ntv);
  }
}

extern "C" void kernel_launch(void* const* d_in, const int* in_sizes, int n_in,
                              void* d_out, int out_size, void* d_ws, size_t ws_size,
                              hipStream_t stream) {
  const float* nf      = (const float*)d_in[0];
  const float* nts     = (const float*)d_in[1];
  const float* adj     = (const float*)d_in[2];
  const float* ets     = (const float*)d_in[3];
  const float* kw      = (const float*)d_in[4];
  const float* kb      = (const float*)d_in[5];
  const float* qw      = (const float*)d_in[6];
  const float* qb      = (const float*)d_in[7];
  const float* vw      = (const float*)d_in[8];
  const float* vb      = (const float*)d_in[9];
  const float* aw      = (const float*)d_in[10];
  const float* ab      = (const float*)d_in[11];
  const float* normw   = (const float*)d_in[12];
  const float* normb   = (const float*)d_in[13];
  const float* rel_pri = (const float*)d_in[14];
  const float* rel_att = (const float*)d_in[15];
  const float* rel_msg = (const float*)d_in[16];
  const float* skip    = (const float*)d_in[17];
  (void)in_sizes; (void)n_in; (void)out_size; (void)ws_size;

  float* ws = (float*)d_ws;
  float* q_ws    = ws;                        // 786432
  float* kr_ws   = q_ws + 786432;             // 3145728
  float* vr_ws   = kr_ws + 3145728;           // 3145728
  float* res_att = vr_ws + 3145728;           // 4718592
  float* att_part= res_att + 4718592;         // 294912 (24 x 12288)
  float* agg_ws  = att_part + 294912 + 12288; // 196608
  // kv scratch aliases res_att (dead until k2 writes it)
  float* kv_k = res_att;                      // 786432
  float* kv_v = res_att + 786432;             // 786432

  hipLaunchKernelGGL(k1a_qkv, dim3(24, 4, 3), dim3(256), 0, stream,
                     nf, qw, qb, kw, kb, vw, vb, q_ws, kv_k, kv_v);
  hipLaunchKernelGGL(k1b_rel, dim3(96, 8), dim3(256), 0, stream,
                     kv_k, kv_v, rel_att, rel_msg, kr_ws, vr_ws, agg_ws, (float*)d_out);
  hipLaunchKernelGGL(k2_att, dim3(48, 8, 4), dim3(256), 0, stream,
                     nts, adj, ets, rel_pri, q_ws, kr_ws, res_att, att_part);
  hipLaunchKernelGGL(kc_agg, dim3(6, 6, 32), dim3(256), 0, stream,
                     nts, adj, ets, rel_pri, q_ws, kr_ws, vr_ws, res_att, att_part, agg_ws);
  hipLaunchKernelGGL(k5_out, dim3(384, 4), dim3(128), 0, stream,
                     agg_ws, nf, nts, aw, ab, normw, normb, skip, (float*)d_out);
}